// Round 1
// baseline (397.247 us; speedup 1.0000x reference)
//
#include <hip/hip_runtime.h>

// Problem constants
// B=4, C=64, H=48, HEADS=2, BSWIN=4, BIG={3,6,12,24}, SMALL={1,2,4,8}, NH=3, L=27, CPH=8
// channel c = scale*16 + head*8 + cph
// sum of windows per (b,head): 16^3 + 8^3 + 4^3 + 2^3 = 4096+512+64+8 = 4680

static constexpr long S1 = 4L * 48 * 24 * 24 * 24;  // pooled D=24 volume, 48 ch (raw ch 16..63)
static constexpr long S2 = 4L * 32 * 12 * 12 * 12;  // pooled D=12 volume, 32 ch (raw ch 32..63)
static constexpr long S3 = 4L * 16 * 6 * 6 * 6;     // pooled D=6 volume, 16 ch (raw ch 48..63)
static constexpr long ATTN_FLOATS = 4L * 2 * 4680 * 27 * 8;

// ---------------------------------------------------------------------------
// 2x2x2 max-pool. blockIdx.y selects tensor (q/k/v). Output layout
// [b][Cout][Dout][Dout][Dout], input [b][Cin][Din][Din][Din] with channel
// offset chOff.
// ---------------------------------------------------------------------------
__global__ void pool2_kernel(const float* __restrict__ in0,
                             const float* __restrict__ in1,
                             const float* __restrict__ in2,
                             float* __restrict__ out, long outStride,
                             int Cin, int chOff, int Cout, int Din, int n)
{
    const float* in = blockIdx.y == 0 ? in0 : (blockIdx.y == 1 ? in1 : in2);
    float* o = out + (long)blockIdx.y * outStride;
    const int Dout = Din >> 1;
    int idx = blockIdx.x * blockDim.x + threadIdx.x;
    if (idx >= n) return;
    int x = idx % Dout;
    int t = idx / Dout;
    int y = t % Dout; t /= Dout;
    int z = t % Dout; t /= Dout;
    int c = t % Cout;
    int b = t / Cout;
    const float* p = in + ((((long)b * Cin + c + chOff) * Din + 2 * z) * Din + 2 * y) * Din + 2 * x;
    float2 a0 = *(const float2*)(p);
    float2 a1 = *(const float2*)(p + Din);
    float2 a2 = *(const float2*)(p + (long)Din * Din);
    float2 a3 = *(const float2*)(p + (long)Din * Din + Din);
    o[idx] = fmaxf(fmaxf(fmaxf(a0.x, a0.y), fmaxf(a1.x, a1.y)),
                   fmaxf(fmaxf(a2.x, a2.y), fmaxf(a3.x, a3.y)));
}

// ---------------------------------------------------------------------------
// Windowed 27-token attention, 8 windows per block of 256 threads.
// Each window handled by one 32-lane group, lanes 0..26 each own one query row.
// ---------------------------------------------------------------------------
template <int S>
__global__ void attn_kernel(const float* __restrict__ qsrc,
                            const float* __restrict__ ksrc,
                            const float* __restrict__ vsrc,
                            const float* __restrict__ rpb,
                            float* __restrict__ attnOut)
{
    constexpr int N1 = (S == 0 ? 16 : S == 1 ? 8 : S == 2 ? 4 : 2);
    constexpr int NW = N1 * N1 * N1;
    constexpr int D  = (S == 0 ? 48 : S == 1 ? 24 : S == 2 ? 12 : 6);
    constexpr int Cs = (S == 0 ? 64 : S == 1 ? 48 : S == 2 ? 32 : 16);
    constexpr int scaleOff = (S == 0 ? 0 : S == 1 ? 4096 : S == 2 ? 4608 : 4672);
    constexpr int WPB = 8;

    __shared__ float tile[WPB][3][27][8];   // q,k,v per window
    __shared__ float bias_lds[2][27][27];

    // bias table: bias[h][m][n] = rpb[REL_IDX(m,n)*2 + h]
    for (int i = threadIdx.x; i < 2 * 729; i += blockDim.x) {
        int h = i / 729;
        int mn = i % 729;
        int m = mn / 27, n = mn % 27;
        int mi = m / 9, mj = (m / 3) % 3, mk = m % 3;
        int ni = n / 9, nj = (n / 3) % 3, nk = n % 3;
        int ridx = (mi - ni + 2) * 25 + (mj - nj + 2) * 5 + (mk - nk + 2);
        bias_lds[h][m][n] = rpb[ridx * 2 + h];
    }

    const int gwin0 = blockIdx.x * WPB;

    // cooperative load of q,k,v tokens for the 8 windows
    for (int i = threadIdx.x; i < WPB * 3 * 216; i += blockDim.x) {
        int w = i / (3 * 216);
        int rem = i % (3 * 216);
        int tz = rem / 216;
        int e = rem % 216;
        int cph = e / 27;
        int tok = e % 27;
        int g = gwin0 + w;
        int b = g / (2 * NW);
        int r2 = g % (2 * NW);
        int head = r2 / NW;
        int win = r2 % NW;
        int Wx = win % N1, Wy = (win / N1) % N1, Wz = win / (N1 * N1);
        int tk = tok % 3, tj = (tok / 3) % 3, ti = tok / 9;
        int Z = Wz * 3 + ti, Y = Wy * 3 + tj, X = Wx * 3 + tk;
        const float* src = tz == 0 ? qsrc : (tz == 1 ? ksrc : vsrc);
        long addr = ((((long)b * Cs + head * 8 + cph) * D + Z) * D + Y) * D + X;
        tile[w][tz][tok][cph] = src[addr];
    }
    __syncthreads();

    const int w = threadIdx.x >> 5;
    const int lane = threadIdx.x & 31;
    if (lane >= 27) return;

    int g = gwin0 + w;
    int b = g / (2 * NW);
    int r2 = g % (2 * NW);
    int head = r2 / NW;
    int win = r2 % NW;
    const int m = lane;

    float qr[8];
#pragma unroll
    for (int c = 0; c < 8; c++) qr[c] = tile[w][0][m][c];

    float s[27];
    float mx = -1e30f;
#pragma unroll
    for (int n = 0; n < 27; n++) {
        float acc = 0.f;
#pragma unroll
        for (int c = 0; c < 8; c++) acc += qr[c] * tile[w][1][n][c];
        acc *= 0.35355339059327373f;  // 1/sqrt(8)
        s[n] = acc;
        mx = fmaxf(mx, acc);
    }
    float sum = 0.f;
#pragma unroll
    for (int n = 0; n < 27; n++) {
        s[n] = __expf(s[n] - mx);
        sum += s[n];
    }
    float rs = 1.0f / sum;

    float o[8] = {0, 0, 0, 0, 0, 0, 0, 0};
#pragma unroll
    for (int n = 0; n < 27; n++) {
        float wgt = s[n] * rs + bias_lds[head][m][n];
#pragma unroll
        for (int c = 0; c < 8; c++) o[c] += wgt * tile[w][2][n][c];
    }

    float* dst = attnOut + (((long)(b * 2 + head) * 4680 + scaleOff + win) * 27 + m) * 8;
#pragma unroll
    for (int c = 0; c < 8; c++) dst[c] = o[c];
}

// ---------------------------------------------------------------------------
// Scatter: trilinear upsample attn tokens back to the 48^3 grid.
// One thread per float4 of output (fully coalesced stores).
// ---------------------------------------------------------------------------
template <int S>
__global__ void scatter_kernel(const float* __restrict__ attn, float* __restrict__ out)
{
    constexpr int bw = (S == 0 ? 3 : S == 1 ? 6 : S == 2 ? 12 : 24);
    constexpr int N1 = 48 / bw;
    constexpr int scaleOff = (S == 0 ? 0 : S == 1 ? 4096 : S == 2 ? 4608 : 4672);
    const float inv = 2.0f / (float)(bw - 1);

    int idx = blockIdx.x * blockDim.x + threadIdx.x;  // exactly 4*16*48*48*12 threads
    int r4 = idx % 12;
    int t = idx / 12;
    int yq = t % 48; t /= 48;
    int p = t % 48; t /= 48;
    int c16 = t % 16;
    int b = t / 16;
    int head = c16 >> 3;
    int cph = c16 & 7;

    int Wz = p / bw;  int wp = p - Wz * bw;
    float posp = wp * inv; int i0p = min((int)posp, 1); float fp = posp - (float)i0p;
    int Wy = yq / bw; int wq = yq - Wy * bw;
    float posq = wq * inv; int i0q = min((int)posq, 1); float fq = posq - (float)i0q;

    float wpv[2] = {1.f - fp, fp};
    float wqv[2] = {1.f - fq, fq};

    float4 res;
    float* rr = (float*)&res;
#pragma unroll
    for (int e = 0; e < 4; e++) {
        int r = r4 * 4 + e;
        int Wx = r / bw; int wr = r - Wx * bw;
        float posr = wr * inv; int i0r = min((int)posr, 1); float fr = posr - (float)i0r;
        float wrv[2] = {1.f - fr, fr};
        int win = (Wz * N1 + Wy) * N1 + Wx;
        const float* base = attn + ((long)(b * 2 + head) * 4680 + scaleOff + win) * 216 + cph;
        float acc = 0.f;
#pragma unroll
        for (int di = 0; di < 2; di++) {
#pragma unroll
            for (int dj = 0; dj < 2; dj++) {
#pragma unroll
                for (int dk = 0; dk < 2; dk++) {
                    int tok = ((i0p + di) * 3 + (i0q + dj)) * 3 + (i0r + dk);
                    acc += wpv[di] * wqv[dj] * wrv[dk] * base[tok * 8];
                }
            }
        }
        rr[e] = acc;
    }
    long oaddr = (((long)(b * 64 + S * 16 + c16) * 48 + p) * 48 + yq) * 48 + (long)r4 * 4;
    *(float4*)(out + oaddr) = res;
}

extern "C" void kernel_launch(void* const* d_in, const int* in_sizes, int n_in,
                              void* d_out, int out_size, void* d_ws, size_t ws_size,
                              hipStream_t stream)
{
    const float* q   = (const float*)d_in[0];
    const float* k   = (const float*)d_in[1];
    const float* v   = (const float*)d_in[2];
    const float* rpb = (const float*)d_in[3];
    float* out = (float*)d_out;

    float* ws = (float*)d_ws;
    float* P1 = ws;                       // 3 tensors x S1
    float* P2 = ws + 3 * S1;              // 3 tensors x S2
    float* P3 = ws + 3 * S1 + 3 * S2;     // 3 tensors x S3
    float* attn = ws + 3 * S1 + 3 * S2 + 3 * S3;  // ATTN_FLOATS

    // Pool stages (hierarchical 2x pooling)
    {
        int n1 = (int)(S1 / 3 * 3 / 3);  // per-tensor elems = 4*48*24^3
        n1 = 4 * 48 * 24 * 24 * 24;
        dim3 g1((n1 + 255) / 256, 3);
        pool2_kernel<<<g1, 256, 0, stream>>>(q, k, v, P1, S1, 64, 16, 48, 48, n1);

        int n2 = 4 * 32 * 12 * 12 * 12;
        dim3 g2((n2 + 255) / 256, 3);
        pool2_kernel<<<g2, 256, 0, stream>>>(P1, P1 + S1, P1 + 2 * S1, P2, S2, 48, 16, 32, 24, n2);

        int n3 = 4 * 16 * 6 * 6 * 6;
        dim3 g3((n3 + 255) / 256, 3);
        pool2_kernel<<<g3, 256, 0, stream>>>(P2, P2 + S2, P2 + 2 * S2, P3, S3, 32, 16, 16, 12, n3);
    }

    // Attention per scale (8 windows per 256-thread block)
    attn_kernel<0><<<4 * 2 * 4096 / 8, 256, 0, stream>>>(q, k, v, rpb, attn);
    attn_kernel<1><<<4 * 2 * 512 / 8, 256, 0, stream>>>(P1, P1 + S1, P1 + 2 * S1, rpb, attn);
    attn_kernel<2><<<4 * 2 * 64 / 8, 256, 0, stream>>>(P2, P2 + S2, P2 + 2 * S2, rpb, attn);
    attn_kernel<3><<<4 * 2 * 8 / 8, 256, 0, stream>>>(P3, P3 + S3, P3 + 2 * S3, rpb, attn);

    // Scatter per scale
    const int nsc = 4 * 16 * 48 * 48 * 12;  // threads (float4 each)
    scatter_kernel<0><<<nsc / 256, 256, 0, stream>>>(attn, out);
    scatter_kernel<1><<<nsc / 256, 256, 0, stream>>>(attn, out);
    scatter_kernel<2><<<nsc / 256, 256, 0, stream>>>(attn, out);
    scatter_kernel<3><<<nsc / 256, 256, 0, stream>>>(attn, out);
}

// Round 2
// 346.930 us; speedup vs baseline: 1.1450x; 1.1450x over previous
//
#include <hip/hip_runtime.h>

// B=4, C=64, H=48, HEADS=2, BSWIN=4, BIG={3,6,12,24}, SMALL={1,2,4,8}, NH=3, L=27, CPH=8
// channel c = scale*16 + head*8 + cph
// windows per (b,head): 16^3+8^3+4^3+2^3 = 4680

static constexpr long S1 = 4L * 48 * 24 * 24 * 24;  // pooled D=24, 48 ch (raw 16..63)
static constexpr long S2 = 4L * 32 * 12 * 12 * 12;  // pooled D=12, 32 ch (raw 32..63)
static constexpr long S3 = 4L * 16 * 6 * 6 * 6;     // pooled D=6, 16 ch (raw 48..63)

// ---------------------------------------------------------------------------
// 2x2x2 max-pool, vectorized: each thread produces OUTW outputs along x.
// Reads 2*OUTW floats x 4 rows (2y x 2z) as float4s. blockIdx.y selects q/k/v.
// ---------------------------------------------------------------------------
template <int OUTW>
__global__ void pool_kernel(const float* __restrict__ in0,
                            const float* __restrict__ in1,
                            const float* __restrict__ in2,
                            float* __restrict__ out, long outStride,
                            int Cin, int chOff, int Cout, int Din, int n)
{
    const float* in = blockIdx.y == 0 ? in0 : (blockIdx.y == 1 ? in1 : in2);
    float* o = out + (long)blockIdx.y * outStride;
    const int Dout = Din >> 1;
    const int QX = Dout / OUTW;
    int idx = blockIdx.x * blockDim.x + threadIdx.x;
    if (idx >= n) return;
    int qx = idx % QX;
    int t = idx / QX;
    int y = t % Dout; t /= Dout;
    int z = t % Dout; t /= Dout;
    int c = t % Cout;
    int b = t / Cout;
    const float* p = in + ((((long)b * Cin + c + chOff) * Din + 2 * z) * Din + 2 * y) * Din
                        + qx * (2 * OUTW);
    const float* rows[4] = { p, p + Din, p + (long)Din * Din, p + (long)Din * Din + Din };

    float v[4][2 * OUTW];
#pragma unroll
    for (int r = 0; r < 4; r++) {
#pragma unroll
        for (int j = 0; j < OUTW / 2; j++) {
            float4 f = *(const float4*)(rows[r] + 4 * j);
            v[r][4 * j + 0] = f.x; v[r][4 * j + 1] = f.y;
            v[r][4 * j + 2] = f.z; v[r][4 * j + 3] = f.w;
        }
    }
    float res[OUTW];
#pragma unroll
    for (int i = 0; i < OUTW; i++) {
        float m0 = fmaxf(v[0][2 * i], v[0][2 * i + 1]);
        float m1 = fmaxf(v[1][2 * i], v[1][2 * i + 1]);
        float m2 = fmaxf(v[2][2 * i], v[2][2 * i + 1]);
        float m3 = fmaxf(v[3][2 * i], v[3][2 * i + 1]);
        res[i] = fmaxf(fmaxf(m0, m1), fmaxf(m2, m3));
    }
    long oaddr = ((((long)b * Cout + c) * Dout + z) * Dout + y) * Dout + qx * OUTW;
    if (OUTW == 4) {
        *(float4*)(o + oaddr) = make_float4(res[0], res[1], res[2], res[3 % OUTW]);
    } else {
        *(float2*)(o + oaddr) = make_float2(res[0], res[1]);
    }
}

// ---------------------------------------------------------------------------
// Windowed 27-token attention. One block per (b, head, Wz, Wy); handles the
// full Wx row of N1 windows with 32*N1 threads. Cooperative loads are
// contiguous segments of 3 consecutive y-rows x full x extent (3*D floats).
// ---------------------------------------------------------------------------
template <int S>
__global__ void attn_kernel(const float* __restrict__ qsrc,
                            const float* __restrict__ ksrc,
                            const float* __restrict__ vsrc,
                            const float* __restrict__ rpb,
                            float* __restrict__ attnOut)
{
    constexpr int N1 = (S == 0 ? 16 : S == 1 ? 8 : S == 2 ? 4 : 2);
    constexpr int D  = 3 * N1;
    constexpr int Cs = (S == 0 ? 64 : S == 1 ? 48 : S == 2 ? 32 : 16);
    constexpr int scaleOff = (S == 0 ? 0 : S == 1 ? 4096 : S == 2 ? 4608 : 4672);
    constexpr int VEC = (S == 3 ? 2 : 4);
    constexpr int SEG = 3 * D;          // floats per contiguous segment
    constexpr int NSEG = 72;            // 3 tensors * 8 cph * 3 z-tokens
    constexpr int TOTV = NSEG * SEG / VEC;

    __shared__ float tile[N1][3][27][8];   // [window][q/k/v][token][cph]
    __shared__ float bias_lds[2][27][27];

    const int b = blockIdx.z;
    const int head = blockIdx.y;
    const int Wz = blockIdx.x / N1;
    const int Wy = blockIdx.x % N1;

    for (int i = threadIdx.x; i < 2 * 729; i += blockDim.x) {
        int h = i / 729;
        int mn = i % 729;
        int m = mn / 27, n = mn % 27;
        int mi = m / 9, mj = (m / 3) % 3, mk = m % 3;
        int ni = n / 9, nj = (n / 3) % 3, nk = n % 3;
        int ridx = (mi - ni + 2) * 25 + (mj - nj + 2) * 5 + (mk - nk + 2);
        bias_lds[h][m][n] = rpb[ridx * 2 + h];
    }

    for (int i = threadIdx.x; i < TOTV; i += blockDim.x) {
        int seg = i / (SEG / VEC);
        int off = (i % (SEG / VEC)) * VEC;
        int tz = seg / 24;
        int rem = seg % 24;
        int cph = rem / 3;
        int zt = rem % 3;
        const float* src = tz == 0 ? qsrc : (tz == 1 ? ksrc : vsrc);
        long base = ((((long)b * Cs + head * 8 + cph) * D + (3 * Wz + zt)) * D + 3 * Wy) * (long)D;
        const float* sp = src + base + off;
        float vals[VEC];
        if (VEC == 4) {
            float4 f = *(const float4*)sp;
            vals[0] = f.x; vals[1] = f.y; vals[2] = f.z; vals[3 % VEC] = f.w;
        } else {
            float2 f = *(const float2*)sp;
            vals[0] = f.x; vals[1] = f.y;
        }
#pragma unroll
        for (int j = 0; j < VEC; j++) {
            int f = off + j;
            int r = f / D;     // y-token 0..2
            int x = f % D;
            tile[x / 3][tz][zt * 9 + r * 3 + (x % 3)][cph] = vals[j];
        }
    }
    __syncthreads();

    const int wx = threadIdx.x >> 5;
    const int lane = threadIdx.x & 31;
    if (lane >= 27) return;
    const int m = lane;

    float qr[8];
#pragma unroll
    for (int c = 0; c < 8; c++) qr[c] = tile[wx][0][m][c];

    float s[27];
    float mx = -1e30f;
#pragma unroll
    for (int n = 0; n < 27; n++) {
        float acc = 0.f;
#pragma unroll
        for (int c = 0; c < 8; c++) acc += qr[c] * tile[wx][1][n][c];
        acc *= 0.35355339059327373f;  // 1/sqrt(8)
        s[n] = acc;
        mx = fmaxf(mx, acc);
    }
    float sum = 0.f;
#pragma unroll
    for (int n = 0; n < 27; n++) {
        s[n] = __expf(s[n] - mx);
        sum += s[n];
    }
    float rs = 1.0f / sum;

    float o[8] = {0, 0, 0, 0, 0, 0, 0, 0};
#pragma unroll
    for (int n = 0; n < 27; n++) {
        float wgt = s[n] * rs + bias_lds[head][m][n];
#pragma unroll
        for (int c = 0; c < 8; c++) o[c] += wgt * tile[wx][2][n][c];
    }

    const int win = (Wz * N1 + Wy) * N1 + wx;
    float* dst = attnOut + (((long)(b * 2 + head) * 4680 + scaleOff + win) * 27 + m) * 8;
    *(float4*)(dst) = make_float4(o[0], o[1], o[2], o[3]);
    *(float4*)(dst + 4) = make_float4(o[4], o[5], o[6], o[7]);
}

// ---------------------------------------------------------------------------
// Fused scatter: trilinear upsample for all 4 scales in one kernel.
// One thread per output float4; scale is block-uniform (derived from channel).
// ---------------------------------------------------------------------------
template <int S>
__device__ __forceinline__ float4 scatter_body(const float* __restrict__ attn,
                                               int b, int head, int cph,
                                               int p, int yq, int r4)
{
    constexpr int bw = (S == 0 ? 3 : S == 1 ? 6 : S == 2 ? 12 : 24);
    constexpr int N1 = 48 / bw;
    constexpr int scaleOff = (S == 0 ? 0 : S == 1 ? 4096 : S == 2 ? 4608 : 4672);
    const float inv = 2.0f / (float)(bw - 1);

    int Wz = p / bw;  int wp = p - Wz * bw;
    float posp = wp * inv; int i0p = min((int)posp, 1); float fp = posp - (float)i0p;
    int Wy = yq / bw; int wq = yq - Wy * bw;
    float posq = wq * inv; int i0q = min((int)posq, 1); float fq = posq - (float)i0q;

    float wpv[2] = {1.f - fp, fp};
    float wqv[2] = {1.f - fq, fq};

    float4 res;
    float* rr = (float*)&res;
#pragma unroll
    for (int e = 0; e < 4; e++) {
        int r = r4 * 4 + e;
        int Wx = r / bw; int wr = r - Wx * bw;
        float posr = wr * inv; int i0r = min((int)posr, 1); float fr = posr - (float)i0r;
        float wrv[2] = {1.f - fr, fr};
        int win = (Wz * N1 + Wy) * N1 + Wx;
        const float* base = attn + ((long)(b * 2 + head) * 4680 + scaleOff + win) * 216 + cph;
        float acc = 0.f;
#pragma unroll
        for (int di = 0; di < 2; di++) {
#pragma unroll
            for (int dj = 0; dj < 2; dj++) {
#pragma unroll
                for (int dk = 0; dk < 2; dk++) {
                    int tok = ((i0p + di) * 3 + (i0q + dj)) * 3 + (i0r + dk);
                    acc += wpv[di] * wqv[dj] * wrv[dk] * base[tok * 8];
                }
            }
        }
        rr[e] = acc;
    }
    return res;
}

__global__ void scatter_all(const float* __restrict__ attn, float* __restrict__ out)
{
    int idx = blockIdx.x * blockDim.x + threadIdx.x;  // 4*64*48*48*12 threads
    int r4 = idx % 12;
    int t = idx / 12;
    int yq = t % 48; t /= 48;
    int p = t % 48; t /= 48;
    int c = t % 64;
    int b = t / 64;
    int scale = c >> 4;
    int head = (c >> 3) & 1;
    int cph = c & 7;

    float4 res;
    switch (scale) {
        case 0: res = scatter_body<0>(attn, b, head, cph, p, yq, r4); break;
        case 1: res = scatter_body<1>(attn, b, head, cph, p, yq, r4); break;
        case 2: res = scatter_body<2>(attn, b, head, cph, p, yq, r4); break;
        default: res = scatter_body<3>(attn, b, head, cph, p, yq, r4); break;
    }
    long oaddr = (((long)(b * 64 + c) * 48 + p) * 48 + yq) * 48 + (long)r4 * 4;
    *(float4*)(out + oaddr) = res;
}

extern "C" void kernel_launch(void* const* d_in, const int* in_sizes, int n_in,
                              void* d_out, int out_size, void* d_ws, size_t ws_size,
                              hipStream_t stream)
{
    const float* q   = (const float*)d_in[0];
    const float* k   = (const float*)d_in[1];
    const float* v   = (const float*)d_in[2];
    const float* rpb = (const float*)d_in[3];
    float* out = (float*)d_out;

    float* ws = (float*)d_ws;
    float* P1 = ws;
    float* P2 = ws + 3 * S1;
    float* P3 = ws + 3 * S1 + 3 * S2;
    float* attn = ws + 3 * S1 + 3 * S2 + 3 * S3;

    // Pool stages (hierarchical 2x pooling), q/k/v via blockIdx.y
    {
        const int n1 = 4 * 48 * 24 * 24 * 6;   // quads (OUTW=4)
        dim3 g1((n1 + 255) / 256, 3);
        pool_kernel<4><<<g1, 256, 0, stream>>>(q, k, v, P1, S1, 64, 16, 48, 48, n1);

        const int n2 = 4 * 32 * 12 * 12 * 3;
        dim3 g2((n2 + 255) / 256, 3);
        pool_kernel<4><<<g2, 256, 0, stream>>>(P1, P1 + S1, P1 + 2 * S1, P2, S2, 48, 16, 32, 24, n2);

        const int n3 = 4 * 16 * 6 * 6 * 3;     // pairs (OUTW=2)
        dim3 g3((n3 + 255) / 256, 3);
        pool_kernel<2><<<g3, 256, 0, stream>>>(P2, P2 + S2, P2 + 2 * S2, P3, S3, 32, 16, 16, 12, n3);
    }

    // Attention per scale: block per (b, head, Wz, Wy), 32*N1 threads
    attn_kernel<0><<<dim3(256, 2, 4), 512, 0, stream>>>(q, k, v, rpb, attn);
    attn_kernel<1><<<dim3(64, 2, 4), 256, 0, stream>>>(P1, P1 + S1, P1 + 2 * S1, rpb, attn);
    attn_kernel<2><<<dim3(16, 2, 4), 128, 0, stream>>>(P2, P2 + S2, P2 + 2 * S2, rpb, attn);
    attn_kernel<3><<<dim3(4, 2, 4), 64, 0, stream>>>(P3, P3 + S3, P3 + 2 * S3, rpb, attn);

    // Fused scatter (all scales)
    const int nsc = 4 * 64 * 48 * 48 * 12;
    scatter_all<<<nsc / 256, 256, 0, stream>>>(attn, out);
}

// Round 3
// 200.408 us; speedup vs baseline: 1.9822x; 1.7311x over previous
//
#include <hip/hip_runtime.h>

// B=4, C=64, H=48, HEADS=2, BSWIN=4, BIG={3,6,12,24}, SMALL={1,2,4,8}, NH=3, L=27, CPH=8
// channel c = scale*16 + head*8 + cph
// windows per (b,head): 16^3+8^3+4^3+2^3 = 4680

static constexpr long S1 = 4L * 48 * 24 * 24 * 24;  // pooled D=24, 48 ch (raw 16..63)
static constexpr long S2 = 4L * 32 * 12 * 12 * 12;  // pooled D=12, 32 ch (raw 32..63)
static constexpr long S3 = 4L * 16 * 6 * 6 * 6;     // pooled D=6, 16 ch (raw 48..63)

// ---------------------------------------------------------------------------
// 2x2x2 max-pool, vectorized: each thread produces OUTW outputs along x.
// ---------------------------------------------------------------------------
template <int OUTW>
__global__ void pool_kernel(const float* __restrict__ in0,
                            const float* __restrict__ in1,
                            const float* __restrict__ in2,
                            float* __restrict__ out, long outStride,
                            int Cin, int chOff, int Cout, int Din, int n)
{
    const float* in = blockIdx.y == 0 ? in0 : (blockIdx.y == 1 ? in1 : in2);
    float* o = out + (long)blockIdx.y * outStride;
    const int Dout = Din >> 1;
    const int QX = Dout / OUTW;
    int idx = blockIdx.x * blockDim.x + threadIdx.x;
    if (idx >= n) return;
    int qx = idx % QX;
    int t = idx / QX;
    int y = t % Dout; t /= Dout;
    int z = t % Dout; t /= Dout;
    int c = t % Cout;
    int b = t / Cout;
    const float* p = in + ((((long)b * Cin + c + chOff) * Din + 2 * z) * Din + 2 * y) * Din
                        + qx * (2 * OUTW);
    const float* rows[4] = { p, p + Din, p + (long)Din * Din, p + (long)Din * Din + Din };

    float v[4][2 * OUTW];
#pragma unroll
    for (int r = 0; r < 4; r++) {
#pragma unroll
        for (int j = 0; j < OUTW / 2; j++) {
            float4 f = *(const float4*)(rows[r] + 4 * j);
            v[r][4 * j + 0] = f.x; v[r][4 * j + 1] = f.y;
            v[r][4 * j + 2] = f.z; v[r][4 * j + 3] = f.w;
        }
    }
    float res[OUTW];
#pragma unroll
    for (int i = 0; i < OUTW; i++) {
        float m0 = fmaxf(v[0][2 * i], v[0][2 * i + 1]);
        float m1 = fmaxf(v[1][2 * i], v[1][2 * i + 1]);
        float m2 = fmaxf(v[2][2 * i], v[2][2 * i + 1]);
        float m3 = fmaxf(v[3][2 * i], v[3][2 * i + 1]);
        res[i] = fmaxf(fmaxf(m0, m1), fmaxf(m2, m3));
    }
    long oaddr = ((((long)b * Cout + c) * Dout + z) * Dout + y) * Dout + qx * OUTW;
    if (OUTW == 4) {
        *(float4*)(o + oaddr) = make_float4(res[0], res[1], res[2], res[3 % OUTW]);
    } else {
        *(float2*)(o + oaddr) = make_float2(res[0], res[1]);
    }
}

// ---------------------------------------------------------------------------
// Windowed 27-token attention. One block per (b, head, Wz, Wy); handles the
// full Wx row of N1 windows with 32*N1 threads.
// ---------------------------------------------------------------------------
template <int S>
__global__ void attn_kernel(const float* __restrict__ qsrc,
                            const float* __restrict__ ksrc,
                            const float* __restrict__ vsrc,
                            const float* __restrict__ rpb,
                            float* __restrict__ attnOut)
{
    constexpr int N1 = (S == 0 ? 16 : S == 1 ? 8 : S == 2 ? 4 : 2);
    constexpr int D  = 3 * N1;
    constexpr int Cs = (S == 0 ? 64 : S == 1 ? 48 : S == 2 ? 32 : 16);
    constexpr int scaleOff = (S == 0 ? 0 : S == 1 ? 4096 : S == 2 ? 4608 : 4672);
    constexpr int VEC = (S == 3 ? 2 : 4);
    constexpr int SEG = 3 * D;          // floats per contiguous segment
    constexpr int NSEG = 72;            // 3 tensors * 8 cph * 3 z-tokens
    constexpr int TOTV = NSEG * SEG / VEC;

    __shared__ float tile[N1][3][27][8];   // [window][q/k/v][token][cph]
    __shared__ float bias_lds[2][27][27];

    const int b = blockIdx.z;
    const int head = blockIdx.y;
    const int Wz = blockIdx.x / N1;
    const int Wy = blockIdx.x % N1;

    for (int i = threadIdx.x; i < 2 * 729; i += blockDim.x) {
        int h = i / 729;
        int mn = i % 729;
        int m = mn / 27, n = mn % 27;
        int mi = m / 9, mj = (m / 3) % 3, mk = m % 3;
        int ni = n / 9, nj = (n / 3) % 3, nk = n % 3;
        int ridx = (mi - ni + 2) * 25 + (mj - nj + 2) * 5 + (mk - nk + 2);
        bias_lds[h][m][n] = rpb[ridx * 2 + h];
    }

    for (int i = threadIdx.x; i < TOTV; i += blockDim.x) {
        int seg = i / (SEG / VEC);
        int off = (i % (SEG / VEC)) * VEC;
        int tz = seg / 24;
        int rem = seg % 24;
        int cph = rem / 3;
        int zt = rem % 3;
        const float* src = tz == 0 ? qsrc : (tz == 1 ? ksrc : vsrc);
        long base = ((((long)b * Cs + head * 8 + cph) * D + (3 * Wz + zt)) * D + 3 * Wy) * (long)D;
        const float* sp = src + base + off;
        float vals[VEC];
        if (VEC == 4) {
            float4 f = *(const float4*)sp;
            vals[0] = f.x; vals[1] = f.y; vals[2] = f.z; vals[3 % VEC] = f.w;
        } else {
            float2 f = *(const float2*)sp;
            vals[0] = f.x; vals[1] = f.y;
        }
#pragma unroll
        for (int j = 0; j < VEC; j++) {
            int f = off + j;
            int r = f / D;     // y-token 0..2
            int x = f % D;
            tile[x / 3][tz][zt * 9 + r * 3 + (x % 3)][cph] = vals[j];
        }
    }
    __syncthreads();

    const int wx = threadIdx.x >> 5;
    const int lane = threadIdx.x & 31;
    if (lane >= 27) return;
    const int m = lane;

    float qr[8];
#pragma unroll
    for (int c = 0; c < 8; c++) qr[c] = tile[wx][0][m][c];

    float s[27];
    float mx = -1e30f;
#pragma unroll
    for (int n = 0; n < 27; n++) {
        float acc = 0.f;
#pragma unroll
        for (int c = 0; c < 8; c++) acc += qr[c] * tile[wx][1][n][c];
        acc *= 0.35355339059327373f;  // 1/sqrt(8)
        s[n] = acc;
        mx = fmaxf(mx, acc);
    }
    float sum = 0.f;
#pragma unroll
    for (int n = 0; n < 27; n++) {
        s[n] = __expf(s[n] - mx);
        sum += s[n];
    }
    float rs = 1.0f / sum;

    float o[8] = {0, 0, 0, 0, 0, 0, 0, 0};
#pragma unroll
    for (int n = 0; n < 27; n++) {
        float wgt = s[n] * rs + bias_lds[head][m][n];
#pragma unroll
        for (int c = 0; c < 8; c++) o[c] += wgt * tile[wx][2][n][c];
    }

    const int win = (Wz * N1 + Wy) * N1 + wx;
    float* dst = attnOut + (((long)(b * 2 + head) * 4680 + scaleOff + win) * 27 + m) * 8;
    *(float4*)(dst) = make_float4(o[0], o[1], o[2], o[3]);
    *(float4*)(dst + 4) = make_float4(o[4], o[5], o[6], o[7]);
}

// ---------------------------------------------------------------------------
// LDS-staged scatter. Block per (b, head, Wz, Wy, z-chunk). Loads the full
// Wx row of windows (contiguous N1*216 floats) into LDS, writes coalesced
// 48-float x-rows. Scale 0 (bw==3==NH) is an identity interp -> pure copy.
// ---------------------------------------------------------------------------
template <int S>
__global__ void scatter_s(const float* __restrict__ attn, float* __restrict__ out)
{
    constexpr int bw = (S == 0 ? 3 : S == 1 ? 6 : S == 2 ? 12 : 24);
    constexpr int N1 = 48 / bw;
    constexpr int scaleOff = (S == 0 ? 0 : S == 1 ? 4096 : S == 2 ? 4608 : 4672);
    constexpr int CZ = (S == 0 ? 3 : S == 1 ? 3 : 1);   // z-rows per block
    constexpr int NZC = bw / CZ;
    constexpr int LDSF = N1 * 216;
    constexpr int NF4 = CZ * bw * 8 * 12;               // output float4s per block

    __shared__ float lds[LDSF];

    const int b = blockIdx.z;
    const int head = blockIdx.y;
    int t = blockIdx.x;
    const int zc = t % NZC; t /= NZC;
    const int Wy = t % N1;
    const int Wz = t / N1;

    const float* src = attn + ((long)(b * 2 + head) * 4680 + scaleOff + (Wz * N1 + Wy) * N1) * 216;
    for (int i = threadIdx.x; i < LDSF / 4; i += blockDim.x)
        *(float4*)(lds + 4 * i) = *(const float4*)(src + 4 * i);
    __syncthreads();

    const float inv = 2.0f / (float)(bw - 1);

    for (int i = threadIdx.x; i < NF4; i += blockDim.x) {
        int x4 = i % 12;
        int t2 = i / 12;
        int cph = t2 % 8; t2 /= 8;
        int y = t2 % bw;
        int zl = t2 / bw;
        int wp = zc * CZ + zl;

        float4 res;
        float* rr = (float*)&res;

        if (S == 0) {
            // identity interpolation: direct copy
#pragma unroll
            for (int e = 0; e < 4; e++) {
                int r = x4 * 4 + e;
                int Wx = r / 3, wr = r % 3;
                rr[e] = lds[(Wx * 27 + (wp * 3 + y) * 3 + wr) * 8 + cph];
            }
        } else {
            float posp = wp * inv; int i0p = min((int)posp, 1); float fp = posp - (float)i0p;
            float posq = y * inv;  int i0q = min((int)posq, 1); float fq = posq - (float)i0q;
            float wpv[2] = {1.f - fp, fp};
            float wqv[2] = {1.f - fq, fq};
#pragma unroll
            for (int e = 0; e < 4; e++) {
                int r = x4 * 4 + e;
                int Wx = r / bw, wr = r % bw;
                float posr = wr * inv; int i0r = min((int)posr, 1); float fr = posr - (float)i0r;
                float wrv[2] = {1.f - fr, fr};
                const float* basep = lds + Wx * 216 + cph;
                float acc = 0.f;
#pragma unroll
                for (int di = 0; di < 2; di++) {
#pragma unroll
                    for (int dj = 0; dj < 2; dj++) {
#pragma unroll
                        for (int dk = 0; dk < 2; dk++) {
                            int tok = ((i0p + di) * 3 + (i0q + dj)) * 3 + (i0r + dk);
                            acc += wpv[di] * wqv[dj] * wrv[dk] * basep[tok * 8];
                        }
                    }
                }
                rr[e] = acc;
            }
        }

        int z = Wz * bw + wp;
        int Y = Wy * bw + y;
        long oaddr = (((long)(b * 64 + S * 16 + head * 8 + cph) * 48 + z) * 48 + Y) * 48 + x4 * 4;
        *(float4*)(out + oaddr) = res;
    }
}

extern "C" void kernel_launch(void* const* d_in, const int* in_sizes, int n_in,
                              void* d_out, int out_size, void* d_ws, size_t ws_size,
                              hipStream_t stream)
{
    const float* q   = (const float*)d_in[0];
    const float* k   = (const float*)d_in[1];
    const float* v   = (const float*)d_in[2];
    const float* rpb = (const float*)d_in[3];
    float* out = (float*)d_out;

    float* ws = (float*)d_ws;
    float* P1 = ws;
    float* P2 = ws + 3 * S1;
    float* P3 = ws + 3 * S1 + 3 * S2;
    float* attn = ws + 3 * S1 + 3 * S2 + 3 * S3;

    // Pool stages (hierarchical 2x pooling), q/k/v via blockIdx.y
    {
        const int n1 = 4 * 48 * 24 * 24 * 6;   // quads (OUTW=4)
        dim3 g1((n1 + 255) / 256, 3);
        pool_kernel<4><<<g1, 256, 0, stream>>>(q, k, v, P1, S1, 64, 16, 48, 48, n1);

        const int n2 = 4 * 32 * 12 * 12 * 3;
        dim3 g2((n2 + 255) / 256, 3);
        pool_kernel<4><<<g2, 256, 0, stream>>>(P1, P1 + S1, P1 + 2 * S1, P2, S2, 48, 16, 32, 24, n2);

        const int n3 = 4 * 16 * 6 * 6 * 3;     // pairs (OUTW=2)
        dim3 g3((n3 + 255) / 256, 3);
        pool_kernel<2><<<g3, 256, 0, stream>>>(P2, P2 + S2, P2 + 2 * S2, P3, S3, 32, 16, 16, 12, n3);
    }

    // Attention per scale: block per (b, head, Wz, Wy), 32*N1 threads
    attn_kernel<0><<<dim3(256, 2, 4), 512, 0, stream>>>(q, k, v, rpb, attn);
    attn_kernel<1><<<dim3(64, 2, 4), 256, 0, stream>>>(P1, P1 + S1, P1 + 2 * S1, rpb, attn);
    attn_kernel<2><<<dim3(16, 2, 4), 128, 0, stream>>>(P2, P2 + S2, P2 + 2 * S2, rpb, attn);
    attn_kernel<3><<<dim3(4, 2, 4), 64, 0, stream>>>(P3, P3 + S3, P3 + 2 * S3, rpb, attn);

    // LDS-staged scatter per scale
    scatter_s<0><<<dim3(16 * 16 * 1, 2, 4), 256, 0, stream>>>(attn, out);   // 2048 blocks
    scatter_s<1><<<dim3(8 * 8 * 2, 2, 4), 256, 0, stream>>>(attn, out);     // 1024 blocks
    scatter_s<2><<<dim3(4 * 4 * 12, 2, 4), 256, 0, stream>>>(attn, out);    // 1536 blocks
    scatter_s<3><<<dim3(2 * 2 * 24, 2, 4), 256, 0, stream>>>(attn, out);    //  768 blocks
}

// Round 4
// 188.712 us; speedup vs baseline: 2.1050x; 1.0620x over previous
//
#include <hip/hip_runtime.h>

// B=4, C=64, H=48, HEADS=2, BSWIN=4, BIG={3,6,12,24}, SMALL={1,2,4,8}, NH=3, L=27, CPH=8
// channel c = scale*16 + head*8 + cph
// windows per (b,head): 16^3+8^3+4^3+2^3 = 4680

static constexpr long S1 = 4L * 48 * 24 * 24 * 24;  // pooled D=24, 48 ch (raw 16..63)
static constexpr long S2 = 4L * 32 * 12 * 12 * 12;  // pooled D=12, 32 ch (raw 32..63)
static constexpr long S3 = 4L * 16 * 6 * 6 * 6;     // pooled D=6, 16 ch (raw 48..63)

// ---------------------------------------------------------------------------
// Stage-1 2x2x2 max-pool (Din=48), plane-staged through LDS.
// Block = 256 threads handles one (tensor, b, c, 2-z-out slab) = 4 input
// planes. Loads are perfectly contiguous float4 streams; x-pair max done in
// registers during load; y/z pooling from LDS; contiguous output writes.
// ---------------------------------------------------------------------------
__global__ void pool48_kernel(const float* __restrict__ in0,
                              const float* __restrict__ in1,
                              const float* __restrict__ in2,
                              float* __restrict__ out, long outStride)
{
    constexpr int ZPB = 2;              // output z-slices per block
    constexpr int PLANES = 2 * ZPB;     // input planes
    constexpr int RSTRIDE = 28;         // padded xp row stride (24 valid)
    __shared__ float xp[PLANES * 48 * RSTRIDE];

    const float* in = blockIdx.y == 0 ? in0 : (blockIdx.y == 1 ? in1 : in2);
    float* o = out + (long)blockIdx.y * outStride;

    int bx = blockIdx.x;
    const int zc = bx % 12; bx /= 12;   // z-chunk (12 = 24/ZPB)
    const int c = bx % 48;
    const int b = bx / 48;
    const int zIn0 = zc * PLANES;

    const float* base = in + ((long)b * 64 + 16 + c) * 110592 + (long)zIn0 * 2304;

    // load 4 planes (4*48*12 float4), x-pool in registers, store float2 to LDS
    for (int i = threadIdx.x; i < PLANES * 48 * 12; i += 256) {
        int p = i / 576;
        int rem = i % 576;
        int r = rem / 12;
        int x4 = rem % 12;
        float4 f = *(const float4*)(base + (long)p * 2304 + r * 48 + 4 * x4);
        float2 m = make_float2(fmaxf(f.x, f.y), fmaxf(f.z, f.w));
        *(float2*)(&xp[(p * 48 + r) * RSTRIDE + 2 * x4]) = m;
    }
    __syncthreads();

    // pool y/z pairs: ZPB*24*24 outputs = ZPB*144 float4
    for (int i = threadIdx.x; i < ZPB * 144; i += 256) {
        int zl = i / 144;
        int rem = i % 144;
        int oy = rem / 6;
        int ox4 = rem % 6;
        const float* p0 = &xp[((2 * zl) * 48 + 2 * oy) * RSTRIDE + 4 * ox4];
        const float* p1 = p0 + RSTRIDE;
        const float* p2 = p0 + 48 * RSTRIDE;
        const float* p3 = p2 + RSTRIDE;
        float4 a = *(const float4*)p0;
        float4 bb = *(const float4*)p1;
        float4 cc = *(const float4*)p2;
        float4 d = *(const float4*)p3;
        float4 r4 = make_float4(fmaxf(fmaxf(a.x, bb.x), fmaxf(cc.x, d.x)),
                                fmaxf(fmaxf(a.y, bb.y), fmaxf(cc.y, d.y)),
                                fmaxf(fmaxf(a.z, bb.z), fmaxf(cc.z, d.z)),
                                fmaxf(fmaxf(a.w, bb.w), fmaxf(cc.w, d.w)));
        long oaddr = (((long)b * 48 + c) * 24 + (zc * ZPB + zl)) * 576 + oy * 24 + 4 * ox4;
        *(float4*)(o + oaddr) = r4;
    }
}

// ---------------------------------------------------------------------------
// Generic 2x2x2 max-pool for the small stages (2,3).
// ---------------------------------------------------------------------------
template <int OUTW>
__global__ void pool_kernel(const float* __restrict__ in0,
                            const float* __restrict__ in1,
                            const float* __restrict__ in2,
                            float* __restrict__ out, long outStride,
                            int Cin, int chOff, int Cout, int Din, int n)
{
    const float* in = blockIdx.y == 0 ? in0 : (blockIdx.y == 1 ? in1 : in2);
    float* o = out + (long)blockIdx.y * outStride;
    const int Dout = Din >> 1;
    const int QX = Dout / OUTW;
    int idx = blockIdx.x * blockDim.x + threadIdx.x;
    if (idx >= n) return;
    int qx = idx % QX;
    int t = idx / QX;
    int y = t % Dout; t /= Dout;
    int z = t % Dout; t /= Dout;
    int c = t % Cout;
    int b = t / Cout;
    const float* p = in + ((((long)b * Cin + c + chOff) * Din + 2 * z) * Din + 2 * y) * Din
                        + qx * (2 * OUTW);
    const float* rows[4] = { p, p + Din, p + (long)Din * Din, p + (long)Din * Din + Din };

    float v[4][2 * OUTW];
#pragma unroll
    for (int r = 0; r < 4; r++) {
#pragma unroll
        for (int j = 0; j < OUTW / 2; j++) {
            float4 f = *(const float4*)(rows[r] + 4 * j);
            v[r][4 * j + 0] = f.x; v[r][4 * j + 1] = f.y;
            v[r][4 * j + 2] = f.z; v[r][4 * j + 3] = f.w;
        }
    }
    float res[OUTW];
#pragma unroll
    for (int i = 0; i < OUTW; i++) {
        float m0 = fmaxf(v[0][2 * i], v[0][2 * i + 1]);
        float m1 = fmaxf(v[1][2 * i], v[1][2 * i + 1]);
        float m2 = fmaxf(v[2][2 * i], v[2][2 * i + 1]);
        float m3 = fmaxf(v[3][2 * i], v[3][2 * i + 1]);
        res[i] = fmaxf(fmaxf(m0, m1), fmaxf(m2, m3));
    }
    long oaddr = ((((long)b * Cout + c) * Dout + z) * Dout + y) * Dout + qx * OUTW;
    if (OUTW == 4) {
        *(float4*)(o + oaddr) = make_float4(res[0], res[1], res[2], res[3 % OUTW]);
    } else {
        *(float2*)(o + oaddr) = make_float2(res[0], res[1]);
    }
}

// ---------------------------------------------------------------------------
// Windowed 27-token attention. One block per (b, head, Wz, Wy); handles the
// full Wx row of N1 windows with 32*N1 threads.
// ---------------------------------------------------------------------------
template <int S>
__global__ void attn_kernel(const float* __restrict__ qsrc,
                            const float* __restrict__ ksrc,
                            const float* __restrict__ vsrc,
                            const float* __restrict__ rpb,
                            float* __restrict__ attnOut)
{
    constexpr int N1 = (S == 0 ? 16 : S == 1 ? 8 : S == 2 ? 4 : 2);
    constexpr int D  = 3 * N1;
    constexpr int Cs = (S == 0 ? 64 : S == 1 ? 48 : S == 2 ? 32 : 16);
    constexpr int scaleOff = (S == 0 ? 0 : S == 1 ? 4096 : S == 2 ? 4608 : 4672);
    constexpr int VEC = (S == 3 ? 2 : 4);
    constexpr int SEG = 3 * D;
    constexpr int NSEG = 72;            // 3 tensors * 8 cph * 3 z-tokens
    constexpr int TOTV = NSEG * SEG / VEC;

    __shared__ float tile[N1][3][27][8];
    __shared__ float bias_lds[2][27][27];

    const int b = blockIdx.z;
    const int head = blockIdx.y;
    const int Wz = blockIdx.x / N1;
    const int Wy = blockIdx.x % N1;

    for (int i = threadIdx.x; i < 2 * 729; i += blockDim.x) {
        int h = i / 729;
        int mn = i % 729;
        int m = mn / 27, n = mn % 27;
        int mi = m / 9, mj = (m / 3) % 3, mk = m % 3;
        int ni = n / 9, nj = (n / 3) % 3, nk = n % 3;
        int ridx = (mi - ni + 2) * 25 + (mj - nj + 2) * 5 + (mk - nk + 2);
        bias_lds[h][m][n] = rpb[ridx * 2 + h];
    }

    for (int i = threadIdx.x; i < TOTV; i += blockDim.x) {
        int seg = i / (SEG / VEC);
        int off = (i % (SEG / VEC)) * VEC;
        int tz = seg / 24;
        int rem = seg % 24;
        int cph = rem / 3;
        int zt = rem % 3;
        const float* src = tz == 0 ? qsrc : (tz == 1 ? ksrc : vsrc);
        long base = ((((long)b * Cs + head * 8 + cph) * D + (3 * Wz + zt)) * D + 3 * Wy) * (long)D;
        const float* sp = src + base + off;
        float vals[VEC];
        if (VEC == 4) {
            float4 f = *(const float4*)sp;
            vals[0] = f.x; vals[1] = f.y; vals[2] = f.z; vals[3 % VEC] = f.w;
        } else {
            float2 f = *(const float2*)sp;
            vals[0] = f.x; vals[1] = f.y;
        }
#pragma unroll
        for (int j = 0; j < VEC; j++) {
            int f = off + j;
            int r = f / D;
            int x = f % D;
            tile[x / 3][tz][zt * 9 + r * 3 + (x % 3)][cph] = vals[j];
        }
    }
    __syncthreads();

    const int wx = threadIdx.x >> 5;
    const int lane = threadIdx.x & 31;
    if (lane >= 27) return;
    const int m = lane;

    float qr[8];
#pragma unroll
    for (int c = 0; c < 8; c++) qr[c] = tile[wx][0][m][c];

    float s[27];
    float mx = -1e30f;
#pragma unroll
    for (int n = 0; n < 27; n++) {
        float acc = 0.f;
#pragma unroll
        for (int c = 0; c < 8; c++) acc += qr[c] * tile[wx][1][n][c];
        acc *= 0.35355339059327373f;  // 1/sqrt(8)
        s[n] = acc;
        mx = fmaxf(mx, acc);
    }
    float sum = 0.f;
#pragma unroll
    for (int n = 0; n < 27; n++) {
        s[n] = __expf(s[n] - mx);
        sum += s[n];
    }
    float rs = 1.0f / sum;

    float o[8] = {0, 0, 0, 0, 0, 0, 0, 0};
#pragma unroll
    for (int n = 0; n < 27; n++) {
        float wgt = s[n] * rs + bias_lds[head][m][n];
#pragma unroll
        for (int c = 0; c < 8; c++) o[c] += wgt * tile[wx][2][n][c];
    }

    const int win = (Wz * N1 + Wy) * N1 + wx;
    float* dst = attnOut + (((long)(b * 2 + head) * 4680 + scaleOff + win) * 27 + m) * 8;
    *(float4*)(dst) = make_float4(o[0], o[1], o[2], o[3]);
    *(float4*)(dst + 4) = make_float4(o[4], o[5], o[6], o[7]);
}

// ---------------------------------------------------------------------------
// LDS-staged scatter, all 4 scales in ONE kernel (block-range dispatch).
// ---------------------------------------------------------------------------
template <int S>
__device__ __forceinline__ void scatter_impl(const float* __restrict__ attn,
                                             float* __restrict__ out,
                                             float* lds, int t, int b, int head,
                                             int tid)
{
    constexpr int bw = (S == 0 ? 3 : S == 1 ? 6 : S == 2 ? 12 : 24);
    constexpr int N1 = 48 / bw;
    constexpr int scaleOff = (S == 0 ? 0 : S == 1 ? 4096 : S == 2 ? 4608 : 4672);
    constexpr int CZ = (S == 0 ? 3 : S == 1 ? 3 : 1);
    constexpr int NZC = bw / CZ;
    constexpr int LDSF = N1 * 216;
    constexpr int NF4 = CZ * bw * 8 * 12;

    const int zc = t % NZC; t /= NZC;
    const int Wy = t % N1;
    const int Wz = t / N1;

    const float* src = attn + ((long)(b * 2 + head) * 4680 + scaleOff + (Wz * N1 + Wy) * N1) * 216;
    for (int i = tid; i < LDSF / 4; i += 256)
        *(float4*)(lds + 4 * i) = *(const float4*)(src + 4 * i);
    __syncthreads();

    const float inv = 2.0f / (float)(bw - 1);

    for (int i = tid; i < NF4; i += 256) {
        int x4 = i % 12;
        int t2 = i / 12;
        int cph = t2 % 8; t2 /= 8;
        int y = t2 % bw;
        int zl = t2 / bw;
        int wp = zc * CZ + zl;

        float4 res;
        float* rr = (float*)&res;

        if (S == 0) {
#pragma unroll
            for (int e = 0; e < 4; e++) {
                int r = x4 * 4 + e;
                int Wx = r / 3, wr = r % 3;
                rr[e] = lds[(Wx * 27 + (wp * 3 + y) * 3 + wr) * 8 + cph];
            }
        } else {
            float posp = wp * inv; int i0p = min((int)posp, 1); float fp = posp - (float)i0p;
            float posq = y * inv;  int i0q = min((int)posq, 1); float fq = posq - (float)i0q;
            float wpv[2] = {1.f - fp, fp};
            float wqv[2] = {1.f - fq, fq};
#pragma unroll
            for (int e = 0; e < 4; e++) {
                int r = x4 * 4 + e;
                int Wx = r / bw, wr = r % bw;
                float posr = wr * inv; int i0r = min((int)posr, 1); float fr = posr - (float)i0r;
                float wrv[2] = {1.f - fr, fr};
                const float* basep = lds + Wx * 216 + cph;
                float acc = 0.f;
#pragma unroll
                for (int di = 0; di < 2; di++) {
#pragma unroll
                    for (int dj = 0; dj < 2; dj++) {
#pragma unroll
                        for (int dk = 0; dk < 2; dk++) {
                            int tok = ((i0p + di) * 3 + (i0q + dj)) * 3 + (i0r + dk);
                            acc += wpv[di] * wqv[dj] * wrv[dk] * basep[tok * 8];
                        }
                    }
                }
                rr[e] = acc;
            }
        }

        int z = Wz * bw + wp;
        int Y = Wy * bw + y;
        long oaddr = (((long)(b * 64 + S * 16 + head * 8 + cph) * 48 + z) * 48 + Y) * 48 + x4 * 4;
        *(float4*)(out + oaddr) = res;
    }
}

__global__ void scatter_all(const float* __restrict__ attn, float* __restrict__ out)
{
    __shared__ float lds[16 * 216];
    const int b = blockIdx.z;
    const int head = blockIdx.y;
    const int bx = blockIdx.x;
    const int tid = threadIdx.x;
    if (bx < 256)      scatter_impl<0>(attn, out, lds, bx,       b, head, tid);
    else if (bx < 384) scatter_impl<1>(attn, out, lds, bx - 256, b, head, tid);
    else if (bx < 576) scatter_impl<2>(attn, out, lds, bx - 384, b, head, tid);
    else               scatter_impl<3>(attn, out, lds, bx - 576, b, head, tid);
}

extern "C" void kernel_launch(void* const* d_in, const int* in_sizes, int n_in,
                              void* d_out, int out_size, void* d_ws, size_t ws_size,
                              hipStream_t stream)
{
    const float* q   = (const float*)d_in[0];
    const float* k   = (const float*)d_in[1];
    const float* v   = (const float*)d_in[2];
    const float* rpb = (const float*)d_in[3];
    float* out = (float*)d_out;

    float* ws = (float*)d_ws;
    float* P1 = ws;
    float* P2 = ws + 3 * S1;
    float* P3 = ws + 3 * S1 + 3 * S2;
    float* attn = ws + 3 * S1 + 3 * S2 + 3 * S3;

    // Pool stage 1: plane-staged, fully contiguous streams
    pool48_kernel<<<dim3(4 * 48 * 12, 3), 256, 0, stream>>>(q, k, v, P1, S1);

    // Pool stages 2,3 (small)
    {
        const int n2 = 4 * 32 * 12 * 12 * 3;
        dim3 g2((n2 + 255) / 256, 3);
        pool_kernel<4><<<g2, 256, 0, stream>>>(P1, P1 + S1, P1 + 2 * S1, P2, S2, 48, 16, 32, 24, n2);

        const int n3 = 4 * 16 * 6 * 6 * 3;
        dim3 g3((n3 + 255) / 256, 3);
        pool_kernel<2><<<g3, 256, 0, stream>>>(P2, P2 + S2, P2 + 2 * S2, P3, S3, 32, 16, 16, 12, n3);
    }

    // Attention per scale
    attn_kernel<0><<<dim3(256, 2, 4), 512, 0, stream>>>(q, k, v, rpb, attn);
    attn_kernel<1><<<dim3(64, 2, 4), 256, 0, stream>>>(P1, P1 + S1, P1 + 2 * S1, rpb, attn);
    attn_kernel<2><<<dim3(16, 2, 4), 128, 0, stream>>>(P2, P2 + S2, P2 + 2 * S2, rpb, attn);
    attn_kernel<3><<<dim3(4, 2, 4), 64, 0, stream>>>(P3, P3 + S3, P3 + 2 * S3, rpb, attn);

    // Fused LDS-staged scatter (all scales, one launch)
    scatter_all<<<dim3(672, 2, 4), 256, 0, stream>>>(attn, out);
}

// Round 5
// 187.768 us; speedup vs baseline: 2.1156x; 1.0050x over previous
//
#include <hip/hip_runtime.h>

// B=4, C=64, H=48, HEADS=2, BSWIN=4, BIG={3,6,12,24}, SMALL={1,2,4,8}, NH=3, L=27, CPH=8
// channel c = scale*16 + head*8 + cph
// windows per (b,head): 16^3+8^3+4^3+2^3 = 4680 (scale0 region of inter unused now)

static constexpr long S1 = 4L * 48 * 24 * 24 * 24;  // pooled D=24, 48 ch (raw 16..63)
static constexpr long S2 = 4L * 32 * 12 * 12 * 12;  // pooled D=12, 32 ch (raw 32..63)
static constexpr long S3 = 4L * 16 * 6 * 6 * 6;     // pooled D=6, 16 ch (raw 48..63)

// ---------------------------------------------------------------------------
// K1: fused pool-stage-1 + attn<0>(+scatter<0>) via block-range dispatch.
//   even bx < 8192  -> attn0 block (aid = bx>>1, 4096 total)
//   odd bx  < 8192  -> pool block  (pid = bx>>1, 0..4095)
//   bx >= 8192      -> pool block  (pid = bx-4096, 4096..6911)
// ---------------------------------------------------------------------------

__device__ __forceinline__ void pool48_body(int pid, float* xp,
                                            const float* __restrict__ q,
                                            const float* __restrict__ k,
                                            const float* __restrict__ v,
                                            float* __restrict__ P1)
{
    constexpr int RSTRIDE = 28;          // padded row stride (24 valid)
    const int tz = pid % 3;
    int rest = pid / 3;
    const int zc = rest % 12; rest /= 12;
    const int c = rest % 48;
    const int b = rest / 48;

    const float* in = tz == 0 ? q : (tz == 1 ? k : v);
    float* o = P1 + (long)tz * S1;
    const float* base = in + ((long)b * 64 + 16 + c) * 110592 + (long)(zc * 4) * 2304;

    // load 4 planes (4*48*12 float4), x-pool in registers, store float2 to LDS
    for (int i = threadIdx.x; i < 4 * 48 * 12; i += 256) {
        int p = i / 576;
        int rem = i % 576;
        int r = rem / 12;
        int x4 = rem % 12;
        float4 f = *(const float4*)(base + (long)p * 2304 + r * 48 + 4 * x4);
        float2 m = make_float2(fmaxf(f.x, f.y), fmaxf(f.z, f.w));
        *(float2*)(&xp[(p * 48 + r) * RSTRIDE + 2 * x4]) = m;
    }
    __syncthreads();

    // pool y/z pairs: 2*24*24 outputs = 288 float4
    for (int i = threadIdx.x; i < 288; i += 256) {
        int zl = i / 144;
        int rem = i % 144;
        int oy = rem / 6;
        int ox4 = rem % 6;
        const float* p0 = &xp[((2 * zl) * 48 + 2 * oy) * RSTRIDE + 4 * ox4];
        const float* p1 = p0 + RSTRIDE;
        const float* p2 = p0 + 48 * RSTRIDE;
        const float* p3 = p2 + RSTRIDE;
        float4 a = *(const float4*)p0;
        float4 bb = *(const float4*)p1;
        float4 cc = *(const float4*)p2;
        float4 d = *(const float4*)p3;
        float4 r4 = make_float4(fmaxf(fmaxf(a.x, bb.x), fmaxf(cc.x, d.x)),
                                fmaxf(fmaxf(a.y, bb.y), fmaxf(cc.y, d.y)),
                                fmaxf(fmaxf(a.z, bb.z), fmaxf(cc.z, d.z)),
                                fmaxf(fmaxf(a.w, bb.w), fmaxf(cc.w, d.w)));
        long oaddr = (((long)b * 48 + c) * 24 + (zc * 2 + zl)) * 576 + oy * 24 + 4 * ox4;
        *(float4*)(o + oaddr) = r4;
    }
}

__device__ __forceinline__ void attn0_body(int aid, float* smem,
                                           const float* __restrict__ qsrc,
                                           const float* __restrict__ ksrc,
                                           const float* __restrict__ vsrc,
                                           const float* __restrict__ rpb,
                                           float* __restrict__ out)
{
    // aid: [half | Wy | Wz | head | b]
    const int half = aid & 1;
    int rest = aid >> 1;
    const int Wy = rest % 16; rest /= 16;
    const int Wz = rest % 16; rest /= 16;
    const int head = rest % 2;
    const int b = rest / 2;

    float* tile = smem;            // [8 wxl][3 tz][27 tok][8 cph] = 5184
    float* bias = smem + 5184;     // [2][27][27] = 1458
    const int tid = threadIdx.x;

    for (int i = tid; i < 2 * 729; i += 256) {
        int h = i / 729;
        int mn = i % 729;
        int m = mn / 27, n = mn % 27;
        int mi = m / 9, mj = (m / 3) % 3, mk = m % 3;
        int ni = n / 9, nj = (n / 3) % 3, nk = n % 3;
        int ridx = (mi - ni + 2) * 25 + (mj - nj + 2) * 5 + (mk - nk + 2);
        bias[i] = rpb[ridx * 2 + h];
    }

    // cooperative q,k,v load: 216 segments (tz,cph,zt,ytok) of 24 floats
    for (int i = tid; i < 1296; i += 256) {
        int seg = i / 6;
        int off = (i % 6) * 4;
        int tz = seg / 72;
        int rem = seg % 72;
        int cph = rem / 9;
        int rem2 = rem % 9;
        int zt = rem2 / 3;
        int r = rem2 % 3;
        const float* src = tz == 0 ? qsrc : (tz == 1 ? ksrc : vsrc);
        long addr = ((((long)b * 64 + head * 8 + cph) * 48 + 3 * Wz + zt) * 48
                     + 3 * Wy + r) * 48 + half * 24 + off;
        float4 f = *(const float4*)(src + addr);
        float vals[4] = {f.x, f.y, f.z, f.w};
#pragma unroll
        for (int j = 0; j < 4; j++) {
            int xl = off + j;
            int wxl = xl / 3, tk = xl % 3;
            int tok = zt * 9 + r * 3 + tk;
            tile[((wxl * 3 + tz) * 27 + tok) * 8 + cph] = vals[j];
        }
    }
    __syncthreads();

    const int wx = tid >> 5;
    const int lane = tid & 31;
    if (lane < 27) {
        const int m = lane;
        const float* tq = tile + (wx * 3 + 0) * 27 * 8;
        const float* tk = tile + (wx * 3 + 1) * 27 * 8;
        const float* tv = tile + (wx * 3 + 2) * 27 * 8;
        float qr[8];
#pragma unroll
        for (int c = 0; c < 8; c++) qr[c] = tq[m * 8 + c];

        float s[27];
        float mx = -1e30f;
#pragma unroll
        for (int n = 0; n < 27; n++) {
            float acc = 0.f;
#pragma unroll
            for (int c = 0; c < 8; c++) acc += qr[c] * tk[n * 8 + c];
            acc *= 0.35355339059327373f;  // 1/sqrt(8)
            s[n] = acc;
            mx = fmaxf(mx, acc);
        }
        float sum = 0.f;
#pragma unroll
        for (int n = 0; n < 27; n++) {
            s[n] = __expf(s[n] - mx);
            sum += s[n];
        }
        float rs = 1.0f / sum;

        float o[8] = {0, 0, 0, 0, 0, 0, 0, 0};
#pragma unroll
        for (int n = 0; n < 27; n++) {
            float wgt = s[n] * rs + bias[(head * 27 + m) * 27 + n];
#pragma unroll
            for (int c = 0; c < 8; c++) o[c] += wgt * tv[n * 8 + c];
        }
        // write o into the q-plane (each thread overwrites only its own row)
        float* to = tile + (wx * 3 + 0) * 27 * 8;
#pragma unroll
        for (int c = 0; c < 8; c++) to[m * 8 + c] = o[c];
    }
    __syncthreads();

    // scatter<0> is identity interp: permuted coalesced write of 432 float4
    for (int i = tid; i < 432; i += 256) {
        int x4i = i % 6;
        int t2 = i / 6;
        int cph = t2 % 8; t2 /= 8;
        int y = t2 % 3;
        int zl = t2 / 3;
        float4 res;
        float* rr = (float*)&res;
#pragma unroll
        for (int e = 0; e < 4; e++) {
            int xl = x4i * 4 + e;
            int wxl = xl / 3, tk = xl % 3;
            int tok = zl * 9 + y * 3 + tk;
            rr[e] = tile[(wxl * 3 + 0) * 27 * 8 + tok * 8 + cph];
        }
        int z = 3 * Wz + zl;
        int Y = 3 * Wy + y;
        long oaddr = (((long)(b * 64 + head * 8 + cph) * 48 + z) * 48 + Y) * 48
                     + half * 24 + x4i * 4;
        *(float4*)(out + oaddr) = res;
    }
}

__global__ void fused_pool_attn0(const float* __restrict__ q,
                                 const float* __restrict__ k,
                                 const float* __restrict__ v,
                                 const float* __restrict__ rpb,
                                 float* __restrict__ P1,
                                 float* __restrict__ out)
{
    __shared__ float smem[6642];  // max(pool 5376, attn 5184+1458)
    const int bx = blockIdx.x;
    if (bx < 8192 && (bx & 1) == 0) {
        attn0_body(bx >> 1, smem, q, k, v, rpb, out);
    } else {
        int pid = (bx < 8192) ? (bx >> 1) : (bx - 4096);
        pool48_body(pid, smem, q, k, v, P1);
    }
}

// ---------------------------------------------------------------------------
// Generic 2x2x2 max-pool for the small stages (2,3).
// ---------------------------------------------------------------------------
template <int OUTW>
__global__ void pool_kernel(const float* __restrict__ in0,
                            const float* __restrict__ in1,
                            const float* __restrict__ in2,
                            float* __restrict__ out, long outStride,
                            int Cin, int chOff, int Cout, int Din, int n)
{
    const float* in = blockIdx.y == 0 ? in0 : (blockIdx.y == 1 ? in1 : in2);
    float* o = out + (long)blockIdx.y * outStride;
    const int Dout = Din >> 1;
    const int QX = Dout / OUTW;
    int idx = blockIdx.x * blockDim.x + threadIdx.x;
    if (idx >= n) return;
    int qx = idx % QX;
    int t = idx / QX;
    int y = t % Dout; t /= Dout;
    int z = t % Dout; t /= Dout;
    int c = t % Cout;
    int b = t / Cout;
    const float* p = in + ((((long)b * Cin + c + chOff) * Din + 2 * z) * Din + 2 * y) * Din
                        + qx * (2 * OUTW);
    const float* rows[4] = { p, p + Din, p + (long)Din * Din, p + (long)Din * Din + Din };

    float v2[4][2 * OUTW];
#pragma unroll
    for (int r = 0; r < 4; r++) {
#pragma unroll
        for (int j = 0; j < OUTW / 2; j++) {
            float4 f = *(const float4*)(rows[r] + 4 * j);
            v2[r][4 * j + 0] = f.x; v2[r][4 * j + 1] = f.y;
            v2[r][4 * j + 2] = f.z; v2[r][4 * j + 3] = f.w;
        }
    }
    float res[OUTW];
#pragma unroll
    for (int i = 0; i < OUTW; i++) {
        float m0 = fmaxf(v2[0][2 * i], v2[0][2 * i + 1]);
        float m1 = fmaxf(v2[1][2 * i], v2[1][2 * i + 1]);
        float m2 = fmaxf(v2[2][2 * i], v2[2][2 * i + 1]);
        float m3 = fmaxf(v2[3][2 * i], v2[3][2 * i + 1]);
        res[i] = fmaxf(fmaxf(m0, m1), fmaxf(m2, m3));
    }
    long oaddr = ((((long)b * Cout + c) * Dout + z) * Dout + y) * Dout + qx * OUTW;
    if (OUTW == 4) {
        *(float4*)(o + oaddr) = make_float4(res[0], res[1], res[2], res[3 % OUTW]);
    } else {
        *(float2*)(o + oaddr) = make_float2(res[0], res[1]);
    }
}

// ---------------------------------------------------------------------------
// Windowed 27-token attention for scales 1..3 (writes the inter buffer).
// ---------------------------------------------------------------------------
template <int S>
__global__ void attn_kernel(const float* __restrict__ qsrc,
                            const float* __restrict__ ksrc,
                            const float* __restrict__ vsrc,
                            const float* __restrict__ rpb,
                            float* __restrict__ attnOut)
{
    constexpr int N1 = (S == 1 ? 8 : S == 2 ? 4 : 2);
    constexpr int D  = 3 * N1;
    constexpr int Cs = (S == 1 ? 48 : S == 2 ? 32 : 16);
    constexpr int scaleOff = (S == 1 ? 4096 : S == 2 ? 4608 : 4672);
    constexpr int VEC = (S == 3 ? 2 : 4);
    constexpr int SEG = 3 * D;
    constexpr int NSEG = 72;
    constexpr int TOTV = NSEG * SEG / VEC;

    __shared__ float tile[N1][3][27][8];
    __shared__ float bias_lds[2][27][27];

    const int b = blockIdx.z;
    const int head = blockIdx.y;
    const int Wz = blockIdx.x / N1;
    const int Wy = blockIdx.x % N1;

    for (int i = threadIdx.x; i < 2 * 729; i += blockDim.x) {
        int h = i / 729;
        int mn = i % 729;
        int m = mn / 27, n = mn % 27;
        int mi = m / 9, mj = (m / 3) % 3, mk = m % 3;
        int ni = n / 9, nj = (n / 3) % 3, nk = n % 3;
        int ridx = (mi - ni + 2) * 25 + (mj - nj + 2) * 5 + (mk - nk + 2);
        bias_lds[h][m][n] = rpb[ridx * 2 + h];
    }

    for (int i = threadIdx.x; i < TOTV; i += blockDim.x) {
        int seg = i / (SEG / VEC);
        int off = (i % (SEG / VEC)) * VEC;
        int tz = seg / 24;
        int rem = seg % 24;
        int cph = rem / 3;
        int zt = rem % 3;
        const float* src = tz == 0 ? qsrc : (tz == 1 ? ksrc : vsrc);
        long base = ((((long)b * Cs + head * 8 + cph) * D + (3 * Wz + zt)) * D + 3 * Wy) * (long)D;
        const float* sp = src + base + off;
        float vals[VEC];
        if (VEC == 4) {
            float4 f = *(const float4*)sp;
            vals[0] = f.x; vals[1] = f.y; vals[2] = f.z; vals[3 % VEC] = f.w;
        } else {
            float2 f = *(const float2*)sp;
            vals[0] = f.x; vals[1] = f.y;
        }
#pragma unroll
        for (int j = 0; j < VEC; j++) {
            int f = off + j;
            int r = f / D;
            int x = f % D;
            tile[x / 3][tz][zt * 9 + r * 3 + (x % 3)][cph] = vals[j];
        }
    }
    __syncthreads();

    const int wx = threadIdx.x >> 5;
    const int lane = threadIdx.x & 31;
    if (lane >= 27) return;
    const int m = lane;

    float qr[8];
#pragma unroll
    for (int c = 0; c < 8; c++) qr[c] = tile[wx][0][m][c];

    float s[27];
    float mx = -1e30f;
#pragma unroll
    for (int n = 0; n < 27; n++) {
        float acc = 0.f;
#pragma unroll
        for (int c = 0; c < 8; c++) acc += qr[c] * tile[wx][1][n][c];
        acc *= 0.35355339059327373f;
        s[n] = acc;
        mx = fmaxf(mx, acc);
    }
    float sum = 0.f;
#pragma unroll
    for (int n = 0; n < 27; n++) {
        s[n] = __expf(s[n] - mx);
        sum += s[n];
    }
    float rs = 1.0f / sum;

    float o[8] = {0, 0, 0, 0, 0, 0, 0, 0};
#pragma unroll
    for (int n = 0; n < 27; n++) {
        float wgt = s[n] * rs + bias_lds[head][m][n];
#pragma unroll
        for (int c = 0; c < 8; c++) o[c] += wgt * tile[wx][2][n][c];
    }

    const int win = (Wz * N1 + Wy) * N1 + wx;
    float* dst = attnOut + (((long)(b * 2 + head) * 4680 + scaleOff + win) * 27 + m) * 8;
    *(float4*)(dst) = make_float4(o[0], o[1], o[2], o[3]);
    *(float4*)(dst + 4) = make_float4(o[4], o[5], o[6], o[7]);
}

// ---------------------------------------------------------------------------
// LDS-staged scatter for scales 1..3 (scale 0 handled by fused attn0).
// ---------------------------------------------------------------------------
template <int S>
__device__ __forceinline__ void scatter_impl(const float* __restrict__ attn,
                                             float* __restrict__ out,
                                             float* lds, int t, int b, int head,
                                             int tid)
{
    constexpr int bw = (S == 1 ? 6 : S == 2 ? 12 : 24);
    constexpr int N1 = 48 / bw;
    constexpr int scaleOff = (S == 1 ? 4096 : S == 2 ? 4608 : 4672);
    constexpr int CZ = (S == 1 ? 3 : 1);
    constexpr int NZC = bw / CZ;
    constexpr int LDSF = N1 * 216;
    constexpr int NF4 = CZ * bw * 8 * 12;

    const int zc = t % NZC; t /= NZC;
    const int Wy = t % N1;
    const int Wz = t / N1;

    const float* src = attn + ((long)(b * 2 + head) * 4680 + scaleOff + (Wz * N1 + Wy) * N1) * 216;
    for (int i = tid; i < LDSF / 4; i += 256)
        *(float4*)(lds + 4 * i) = *(const float4*)(src + 4 * i);
    __syncthreads();

    const float inv = 2.0f / (float)(bw - 1);

    for (int i = tid; i < NF4; i += 256) {
        int x4 = i % 12;
        int t2 = i / 12;
        int cph = t2 % 8; t2 /= 8;
        int y = t2 % bw;
        int zl = t2 / bw;
        int wp = zc * CZ + zl;

        float posp = wp * inv; int i0p = min((int)posp, 1); float fp = posp - (float)i0p;
        float posq = y * inv;  int i0q = min((int)posq, 1); float fq = posq - (float)i0q;
        float wpv[2] = {1.f - fp, fp};
        float wqv[2] = {1.f - fq, fq};
        float4 res;
        float* rr = (float*)&res;
#pragma unroll
        for (int e = 0; e < 4; e++) {
            int r = x4 * 4 + e;
            int Wx = r / bw, wr = r % bw;
            float posr = wr * inv; int i0r = min((int)posr, 1); float fr = posr - (float)i0r;
            float wrv[2] = {1.f - fr, fr};
            const float* basep = lds + Wx * 216 + cph;
            float acc = 0.f;
#pragma unroll
            for (int di = 0; di < 2; di++) {
#pragma unroll
                for (int dj = 0; dj < 2; dj++) {
#pragma unroll
                    for (int dk = 0; dk < 2; dk++) {
                        int tok = ((i0p + di) * 3 + (i0q + dj)) * 3 + (i0r + dk);
                        acc += wpv[di] * wqv[dj] * wrv[dk] * basep[tok * 8];
                    }
                }
            }
            rr[e] = acc;
        }

        int z = Wz * bw + wp;
        int Y = Wy * bw + y;
        long oaddr = (((long)(b * 64 + S * 16 + head * 8 + cph) * 48 + z) * 48 + Y) * 48 + x4 * 4;
        *(float4*)(out + oaddr) = res;
    }
}

__global__ void scatter_all(const float* __restrict__ attn, float* __restrict__ out)
{
    __shared__ float lds[8 * 216];
    const int b = blockIdx.z;
    const int head = blockIdx.y;
    const int bx = blockIdx.x;
    const int tid = threadIdx.x;
    if (bx < 128)      scatter_impl<1>(attn, out, lds, bx,       b, head, tid);
    else if (bx < 320) scatter_impl<2>(attn, out, lds, bx - 128, b, head, tid);
    else               scatter_impl<3>(attn, out, lds, bx - 320, b, head, tid);
}

extern "C" void kernel_launch(void* const* d_in, const int* in_sizes, int n_in,
                              void* d_out, int out_size, void* d_ws, size_t ws_size,
                              hipStream_t stream)
{
    const float* q   = (const float*)d_in[0];
    const float* k   = (const float*)d_in[1];
    const float* v   = (const float*)d_in[2];
    const float* rpb = (const float*)d_in[3];
    float* out = (float*)d_out;

    float* ws = (float*)d_ws;
    float* P1 = ws;
    float* P2 = ws + 3 * S1;
    float* P3 = ws + 3 * S1 + 3 * S2;
    float* attn = ws + 3 * S1 + 3 * S2 + 3 * S3;

    // K1: pool stage 1 (6912 blk) co-launched with fused attn0+scatter0 (4096 blk)
    fused_pool_attn0<<<11008, 256, 0, stream>>>(q, k, v, rpb, P1, out);

    // Pool stages 2,3
    {
        const int n2 = 4 * 32 * 12 * 12 * 3;
        dim3 g2((n2 + 255) / 256, 3);
        pool_kernel<4><<<g2, 256, 0, stream>>>(P1, P1 + S1, P1 + 2 * S1, P2, S2, 48, 16, 32, 24, n2);

        const int n3 = 4 * 16 * 6 * 6 * 3;
        dim3 g3((n3 + 255) / 256, 3);
        pool_kernel<2><<<g3, 256, 0, stream>>>(P2, P2 + S2, P2 + 2 * S2, P3, S3, 32, 16, 16, 12, n3);
    }

    // Attention scales 1..3 -> inter
    attn_kernel<1><<<dim3(64, 2, 4), 256, 0, stream>>>(P1, P1 + S1, P1 + 2 * S1, rpb, attn);
    attn_kernel<2><<<dim3(16, 2, 4), 128, 0, stream>>>(P2, P2 + S2, P2 + 2 * S2, rpb, attn);
    attn_kernel<3><<<dim3(4, 2, 4), 64, 0, stream>>>(P3, P3 + S3, P3 + 2 * S3, rpb, attn);

    // Scatter scales 1..3
    scatter_all<<<dim3(416, 2, 4), 256, 0, stream>>>(attn, out);
}